// Round 10
// baseline (2835.823 us; speedup 1.0000x reference)
//
#include <hip/hip_runtime.h>
#include <hip/hip_bf16.h>

#define T_STEPS 2048
#define BATCH   1024
#define NUNITS  128
#define ROWS    8
#define LOG2E   1.4426950408889634f

typedef __attribute__((ext_vector_type(8))) __bf16 bf16x8;
typedef __attribute__((ext_vector_type(4))) float  f32x4;
typedef __attribute__((ext_vector_type(2))) int    i32x2;

__device__ __forceinline__ float sigm_pre(float xs) {
    return __builtin_amdgcn_rcpf(1.0f + __builtin_amdgcn_exp2f(-xs));
}
__device__ __forceinline__ float tanh_pre(float xs) {
    return fmaf(-2.0f, __builtin_amdgcn_rcpf(1.0f + __builtin_amdgcn_exp2f(xs)), 1.0f);
}
// lanes 0-31 = a[self], lanes 32-63 = b[lane-32]  (verified R7)
__device__ __forceinline__ float swap_lo(float a, float b) {
    i32x2 r = __builtin_amdgcn_permlane32_swap(__builtin_bit_cast(int, a),
                                               __builtin_bit_cast(int, b),
                                               false, false);
    return __builtin_bit_cast(float, r[0]);
}

// ---------------- embedding pre-pass (HBM-bound, unchanged/verified)
__global__ __launch_bounds__(256) void emb_kernel(const float* __restrict__ x,
                                                  const float* __restrict__ Wemb,
                                                  const float* __restrict__ bemb,
                                                  ushort* __restrict__ e_out) {
    int g = blockIdx.x * 256 + threadIdx.x;   // g = t*1024 + b
    int t = g >> 10;
    int b = g & 1023;
    const float* xr = x + ((size_t)b * T_STEPS + t) * 64;

    float4 xv[16];
#pragma unroll
    for (int i = 0; i < 16; i++) xv[i] = ((const float4*)xr)[i];

    float acc[24];
#pragma unroll
    for (int j = 0; j < 24; j++) acc[j] = bemb[j];

#pragma unroll
    for (int d = 0; d < 64; d++) {
        float xs = ((const float*)xv)[d];
#pragma unroll
        for (int j = 0; j < 24; j++) acc[j] = fmaf(xs, Wemb[d * 24 + j], acc[j]);
    }

    uint outp[12];
#pragma unroll
    for (int p = 0; p < 12; p++) {
        float lo = __builtin_amdgcn_rcpf(1.0f + __builtin_amdgcn_exp2f(-LOG2E * acc[2 * p]));
        float hi = __builtin_amdgcn_rcpf(1.0f + __builtin_amdgcn_exp2f(-LOG2E * acc[2 * p + 1]));
        ushort ulo = __builtin_bit_cast(ushort, (__bf16)lo);
        ushort uhi = __builtin_bit_cast(ushort, (__bf16)hi);
        outp[p] = (uint)ulo | ((uint)uhi << 16);
    }
    uint4* dst = (uint4*)(e_out + (size_t)g * 24);
#pragma unroll
    for (int q = 0; q < 3; q++) dst[q] = ((const uint4*)outp)[q];
}

// ---------------- recurrent kernel: 128 blocks x 512 threads (8 waves), 8 rows/block.
// Two ANTI-PHASED groups (A = rows 0-3, B = rows 4-7), software-pipelined:
// each barrier interval = { issue other-group z-reads ; compute this group from
// regs read last interval ; write h ; lgkmcnt(0) (free: reads aged); s_barrier }.
// Read latency hides under the other group's MFMA+trans. A=z (regs from LDS),
// B=W (regs); D[m=row][n=unit]; valid m=0-3 -> lanes 0-15 regs 0-3; compaction
// via one permlane32_swap pair -> lanes 0-15 rows {0,1}, lanes 32-47 rows {2,3}.
// z layout [grp][ks4][kg4][row6(pad)][8]: masked 16-lane b128 reads ~conflict-free.
__global__ __launch_bounds__(512, 2) void lstm_kernel(
    const ushort* __restrict__ e_ws,
    const float* __restrict__ Wf, const float* __restrict__ bf_,
    const float* __restrict__ Wi, const float* __restrict__ bi_,
    const float* __restrict__ Wg, const float* __restrict__ bg_,
    const float* __restrict__ Wo, const float* __restrict__ bo_,
    const float* __restrict__ Wout, const float* __restrict__ bout,
    float* __restrict__ out) {
    __shared__ __align__(16) __bf16 zbuf[2][4][4][6][8];   // 3 KiB; strides: grp768,ks192,kg48,row8

    const int tid  = threadIdx.x;
    const int lane = tid & 63;
    const int wv   = tid >> 6;      // 0..7 -> unit tile [16wv,16wv+16)
    const int l15  = lane & 15;
    const int kg   = lane >> 4;     // 0..3
    const int r0   = blockIdx.x * ROWS;

    // ---- persistent W fragments (B operand), pre-scaled by exp2 constants
    const float* Wp[4] = {Wf, Wi, Wg, Wo};
    const float gsc[4] = {LOG2E, LOG2E, 2.0f * LOG2E, LOG2E};
    const int ucol = wv * 16 + l15;
    bf16x8 wreg[4][5];
#pragma unroll
    for (int gt = 0; gt < 4; gt++) {
#pragma unroll
        for (int ks = 0; ks < 5; ks++) {
#pragma unroll
            for (int j = 0; j < 8; j++) {
                int k = ks * 32 + kg * 8 + j;
                float v = 0.0f;
                if (k < 128) v = Wp[gt][(24 + k) * NUNITS + ucol];
                else if (k < 152) v = Wp[gt][(k - 128) * NUNITS + ucol];
                wreg[gt][ks][j] = (__bf16)(v * gsc[gt]);
            }
        }
    }
    const float* Bp[4] = {bf_, bi_, bg_, bo_};
    f32x4 bias[4];
#pragma unroll
    for (int gt = 0; gt < 4; gt++) {
        float bv = Bp[gt][ucol] * gsc[gt];
#pragma unroll
        for (int r = 0; r < 4; r++) bias[gt][r] = bv;
    }
    const f32x4 zero4 = {0.0f, 0.0f, 0.0f, 0.0f};

    // zero both z buffers (h0 = 0)
    for (int i = tid; i < 2 * 4 * 4 * 6 * 8; i += 512) ((__bf16*)zbuf)[i] = (__bf16)0.0f;

    __bf16* zbase = &zbuf[0][0][0][0][0];
    const bool rd_act = (l15 < 4);
    const __bf16* rdA = zbase + kg * 48 + l15 * 8;          // + ks*192
    const __bf16* rdB = rdA + 768;
    const int w_m0 = (lane >= 32) ? 2 : 0;
    const bool wact = (((lane >> 4) & 1) == 0);             // lanes 0-15, 32-47
    __bf16* wA = zbase + (ucol >> 5) * 192 + ((ucol >> 3) & 3) * 48 + w_m0 * 8 + (ucol & 7);
    __bf16* wB = wA + 768;

    // ---- e prefetch rings, depth 2 per group (lanes kg<3, l15<4)
    const bool eload = (kg < 3) && rd_act;
    const ushort* elbA = e_ws + ((size_t)(r0 + (l15 & 3)) * 24 + kg * 8);
    const ushort* elbB = elbA + 4 * 24;
    bf16x8 eA0, eA1, eB0, eB1;
#pragma unroll
    for (int j = 0; j < 8; j++) { eA0[j] = (__bf16)0; eA1[j] = (__bf16)0; eB0[j] = (__bf16)0; eB1[j] = (__bf16)0; }
    if (eload) {
        eA0 = *(const bf16x8*)(const void*)(elbA);
        eA1 = *(const bf16x8*)(const void*)(elbA + 24576);
        eB0 = *(const bf16x8*)(const void*)(elbB);
        eB1 = *(const bf16x8*)(const void*)(elbB + 24576);
    }

    __syncthreads();

    // hoisted e-acc for step 0, then refill ring slot 0 with e(2)
    f32x4 eaccA[4], eaccB[4];
#pragma unroll
    for (int gt = 0; gt < 4; gt++) {
        eaccA[gt] = __builtin_amdgcn_mfma_f32_16x16x32_bf16(eA0, wreg[gt][4], bias[gt], 0, 0, 0);
        eaccB[gt] = __builtin_amdgcn_mfma_f32_16x16x32_bf16(eB0, wreg[gt][4], bias[gt], 0, 0, 0);
    }
    if (eload) {
        eA0 = *(const bf16x8*)(const void*)(elbA + 2 * 24576);
        eB0 = *(const bf16x8*)(const void*)(elbB + 2 * 24576);
    }

    // z-regs (consumed group regs); masked lanes stay zero forever
    bf16x8 zrA[4], zrB[4];
#pragma unroll
    for (int q = 0; q < 4; q++)
#pragma unroll
        for (int j = 0; j < 8; j++) { zrA[q][j] = (__bf16)0; zrB[q][j] = (__bf16)0; }

    float cA0 = 0, cA1 = 0, cB0 = 0, cB1 = 0;

    auto HALF = [&](int t, __bf16* zw, const __bf16* zo_rd,
                    bf16x8 (&zr)[4], bf16x8 (&ozr)[4],
                    f32x4 (&eacc)[4], bf16x8& ering, const ushort* elb,
                    float& cc0, float& cc1) {
        // 1. issue OTHER group's z reads (consumed next half; latency hides here)
        if (rd_act) {
            ozr[0] = *(const bf16x8*)(const void*)(zo_rd);
            ozr[1] = *(const bf16x8*)(const void*)(zo_rd + 192);
            ozr[2] = *(const bf16x8*)(const void*)(zo_rd + 384);
            ozr[3] = *(const bf16x8*)(const void*)(zo_rd + 576);
        }
        // 2. compute this group: dual 2-deep chains, C = hoisted e-acc
        f32x4 ca[4], cb[4];
#pragma unroll
        for (int gt = 0; gt < 4; gt++) {
            ca[gt] = __builtin_amdgcn_mfma_f32_16x16x32_bf16(zr[0], wreg[gt][0], eacc[gt], 0, 0, 0);
            cb[gt] = __builtin_amdgcn_mfma_f32_16x16x32_bf16(zr[1], wreg[gt][1], zero4, 0, 0, 0);
        }
#pragma unroll
        for (int gt = 0; gt < 4; gt++) {
            ca[gt] = __builtin_amdgcn_mfma_f32_16x16x32_bf16(zr[2], wreg[gt][2], ca[gt], 0, 0, 0);
            cb[gt] = __builtin_amdgcn_mfma_f32_16x16x32_bf16(zr[3], wreg[gt][3], cb[gt], 0, 0, 0);
        }
        // 3. refill e-acc (for step t+1) in place; reload ring reg with e(t+3)
#pragma unroll
        for (int gt = 0; gt < 4; gt++)
            eacc[gt] = __builtin_amdgcn_mfma_f32_16x16x32_bf16(ering, wreg[gt][4], bias[gt], 0, 0, 0);
        {
            int tf = t + 3; if (tf > T_STEPS - 1) tf = T_STEPS - 1;
            if (eload) ering = *(const bf16x8*)(const void*)(elb + (size_t)tf * 24576);
        }
        // 4. merge chains + compact: lanes0-15 rows{0,1}, lanes32-47 rows{2,3}
        float g0[4], g1[4];
#pragma unroll
        for (int gt = 0; gt < 4; gt++) {
            f32x4 gs = ca[gt] + cb[gt];
            g0[gt] = swap_lo(gs[0], gs[2]);
            g1[gt] = swap_lo(gs[1], gs[3]);
        }
        float fg0 = sigm_pre(g0[0]), fg1 = sigm_pre(g1[0]);
        float ig0 = sigm_pre(g0[1]), ig1 = sigm_pre(g1[1]);
        float gg0 = tanh_pre(g0[2]), gg1 = tanh_pre(g1[2]);
        float og0 = sigm_pre(g0[3]), og1 = sigm_pre(g1[3]);
        cc0 = fmaf(cc0, fg0, ig0 * gg0);
        cc1 = fmaf(cc1, fg1, ig1 * gg1);
        float h0 = tanh_pre(2.0f * LOG2E * cc0) * og0;
        float h1 = tanh_pre(2.0f * LOG2E * cc1) * og1;
        if (wact) {
            zw[0] = (__bf16)h0;   // row w_m0
            zw[8] = (__bf16)h1;   // row w_m0+1
        }
        // 5. writes done (reads aged ~full compute phase -> lgkmcnt(0) ~free);
        //    vmem e-prefetch stays in flight across the raw barrier
        asm volatile("s_waitcnt lgkmcnt(0)" ::: "memory");
        __builtin_amdgcn_s_barrier();
        __builtin_amdgcn_sched_barrier(0);
    };

    for (int t = 0; t < T_STEPS; t += 2) {
        HALF(t,     wB, rdA, zrB, zrA, eaccB, eB1, elbB, cB0, cB1);  // compute B(t),   read zA
        HALF(t,     wA, rdB, zrA, zrB, eaccA, eA1, elbA, cA0, cA1);  // compute A(t),   read zB
        HALF(t + 1, wB, rdA, zrB, zrA, eaccB, eB0, elbB, cB0, cB1);  // compute B(t+1), read zA
        HALF(t + 1, wA, rdB, zrA, zrB, eaccA, eA0, elbA, cA0, cA1);  // compute A(t+1), read zB
    }

    // h_last: group g rows in zbuf[g][k>>5][(k>>3)&3][row][k&7]
    if (tid < ROWS) {
        int g = tid >> 2, lr = tid & 3;
        float s = bout[0];
#pragma unroll
        for (int k = 0; k < NUNITS; k++)
            s += (float)zbuf[g][k >> 5][(k >> 3) & 3][lr][k & 7] * Wout[k];
        out[r0 + tid] = __builtin_amdgcn_rcpf(1.0f + __builtin_amdgcn_exp2f(-LOG2E * s));
    }
}

extern "C" void kernel_launch(void* const* d_in, const int* in_sizes, int n_in,
                              void* d_out, int out_size, void* d_ws, size_t ws_size,
                              hipStream_t stream) {
    const float* x     = (const float*)d_in[0];
    const float* Wemb  = (const float*)d_in[1];
    const float* bemb  = (const float*)d_in[2];
    const float* Wf    = (const float*)d_in[3];
    const float* bf_   = (const float*)d_in[4];
    const float* Wi    = (const float*)d_in[5];
    const float* bi_   = (const float*)d_in[6];
    const float* Wg    = (const float*)d_in[7];
    const float* bg_   = (const float*)d_in[8];
    const float* Wo    = (const float*)d_in[9];
    const float* bo_   = (const float*)d_in[10];
    const float* Wout  = (const float*)d_in[11];
    const float* bout  = (const float*)d_in[12];
    float* out = (float*)d_out;
    ushort* e_ws = (ushort*)d_ws;   // [T][B][24] bf16, ~96 MB

    int nrows = BATCH * T_STEPS;
    emb_kernel<<<nrows / 256, 256, 0, stream>>>(x, Wemb, bemb, e_ws);
    lstm_kernel<<<BATCH / ROWS, 512, 0, stream>>>(e_ws, Wf, bf_, Wi, bi_, Wg, bg_,
                                                  Wo, bo_, Wout, bout, out);
}